// Round 4
// baseline (117.144 us; speedup 1.0000x reference)
//
#include <hip/hip_runtime.h>
#include <math.h>

#define BB 4
#define NN 128
#define LK 16384      // n*n
#define DD 64
#define HH 4
#define DHH 16
#define TI2 32        // q-rows per block
#define KROWS 64      // staged k rows per chunk (K1)
#define KPAD 68       // floats per LDS row (272B) -> b128 reads hit the 8-phase floor
#define QK_SCALE 0.3606737602f   // 0.25 * log2(e): exp(d/4) == exp2(d*QK_SCALE)

__device__ __forceinline__ float fexp2(float x){
#if __has_builtin(__builtin_amdgcn_exp2f)
  return __builtin_amdgcn_exp2f(x);   // v_exp_f32
#else
  return __expf(x * 0.6931471806f);
#endif
}

// ---- mask dtype classification via wave ballots: 0=int32, 1=uint8, 2=float32
__device__ __forceinline__ int compute_mode(const void* __restrict__ qmask){
  const unsigned int* w = (const unsigned int*)qmask;
  const int t = threadIdx.x & 63;
  int u8 = 0, i32 = 0, f32 = 0;
  #pragma unroll
  for (int rep = 0; rep < 2; ++rep){
    const unsigned int x = w[t + rep*64];   // first 512B: in-bounds for every dtype
    const bool one  = (x == 1u);
    const bool fone = (x == 0x3f800000u);
    const bool nz   = (x != 0u);
    u8  += __popcll(__ballot(nz && !one && !fone));
    i32 += __popcll(__ballot(one));
    f32 += __popcll(__ballot(fone));
  }
  int mode = 0;
  if (u8 > i32 && u8 > f32) mode = 1;
  else if (f32 > i32) mode = 2;
  return mode;
}

__device__ __forceinline__ bool mget(const void* __restrict__ p, int idx, int mode){
  if (mode == 1) return ((const unsigned char*)p)[idx] != 0;
  if (mode == 2) return ((const float*)p)[idx] != 0.0f;
  return ((const int*)p)[idx] != 0;
}

__device__ __forceinline__ float dot16(float4 q0, float4 q1, float4 q2, float4 q3,
                                       float4 k0, float4 k1, float4 k2, float4 k3){
  float d;
  d = q0.x*k0.x;         d = fmaf(q0.y,k0.y,d); d = fmaf(q0.z,k0.z,d); d = fmaf(q0.w,k0.w,d);
  d = fmaf(q1.x,k1.x,d); d = fmaf(q1.y,k1.y,d); d = fmaf(q1.z,k1.z,d); d = fmaf(q1.w,k1.w,d);
  d = fmaf(q2.x,k2.x,d); d = fmaf(q2.y,k2.y,d); d = fmaf(q2.z,k2.z,d); d = fmaf(q2.w,k2.w,d);
  d = fmaf(q3.x,k3.x,d); d = fmaf(q3.y,k3.y,d); d = fmaf(q3.z,k3.z,d); d = fmaf(q3.w,k3.w,d);
  return d;
}

// stage KROWS k-records (256B each) into padded LDS, pre-scaled; coalesced reads
__device__ __forceinline__ void stage_k(const float* __restrict__ kA, int b, int lbase,
                                        float* __restrict__ ldsK){
  const int t = threadIdx.x;
  const float4* src = (const float4*)(kA + ((size_t)(b*LK + lbase))*DD);
  #pragma unroll
  for (int p = 0; p < 4; ++p){
    const int f = p*256 + t;          // float4 index 0..1023 over 16KB
    float4 v = src[f];
    v.x *= QK_SCALE; v.y *= QK_SCALE; v.z *= QK_SCALE; v.w *= QK_SCALE;
    *(float4*)(ldsK + (f >> 4)*KPAD + (f & 15)*4) = v;
  }
}

// ---- pass 1: per-(h,row) sum of exp2 over this block's l-span ----
// wave = head; lane = staged l. q via scalar loads (uniform addr), k from LDS regs.
__global__ __launch_bounds__(256) void k1_rowsum(
    const float* __restrict__ qA, const float* __restrict__ kA,
    const void* __restrict__ qm, const void* __restrict__ km,
    float* __restrict__ partials)
{
  __shared__ float ldsK[KROWS*KPAD];
  __shared__ float ldsP[HH][TI2];
  const int mode = compute_mode(qm);
  const int nl = gridDim.x;
  const int chunks = (LK/nl)/KROWS;
  const int lc = blockIdx.x, it = blockIdx.y, b = blockIdx.z;
  const int t = threadIdx.x, w = t >> 6, ll = t & 63;
  const int hs = __builtin_amdgcn_readfirstlane(w);    // uniform head index
  const int ibase = it*TI2;
  const float* qbase = qA + ((size_t)(b*NN + ibase))*DD + hs*DHH;

  float s[TI2];
  #pragma unroll
  for (int i = 0; i < TI2; ++i) s[i] = 0.0f;

  const int lbase0 = lc*(LK/nl);
  for (int jj = 0; jj < chunks; ++jj){
    if (jj) __syncthreads();
    stage_k(kA, b, lbase0 + jj*KROWS, ldsK);
    __syncthreads();

    const int l  = lbase0 + jj*KROWS + ll;
    const int jn = l >> 7, kn = l & 127;
    const bool kv = (jn != kn) && mget(km, b*LK + l, mode);
    unsigned vmask = kv ? 0xFFFFFFFFu : 0u;
    if ((unsigned)(jn - ibase) < TI2) vmask &= ~(1u << (jn - ibase));
    if ((unsigned)(kn - ibase) < TI2) vmask &= ~(1u << (kn - ibase));

    const float* kp = ldsK + ll*KPAD + hs*DHH;
    const float4 k0 = *(const float4*)(kp),    k1 = *(const float4*)(kp+4),
                 k2 = *(const float4*)(kp+8),  k3 = *(const float4*)(kp+12);

    #pragma unroll 8
    for (int i = 0; i < TI2; ++i){
      const float4* qp = (const float4*)(qbase + i*DD);   // uniform -> s_load
      float d = dot16(qp[0], qp[1], qp[2], qp[3], k0, k1, k2, k3);
      d = (vmask & (1u << i)) ? d : -INFINITY;            // exp2(-inf)=0
      s[i] += fexp2(d);
    }
  }

  #pragma unroll
  for (int i = 0; i < TI2; ++i){
    float v = s[i];
    #pragma unroll
    for (int off = 32; off; off >>= 1) v += __shfl_xor(v, off);
    if (ll == 0) ldsP[w][i] = v;
  }
  __syncthreads();
  if (t < HH*TI2){                 // t = h*32 + i
    const int h = t >> 5, i = t & 31;
    const bool qv = mget(qm, b*NN + ibase + i, mode);
    partials[lc*(BB*HH*NN) + (b*HH + h)*NN + ibase + i] = qv ? ldsP[h][i] : 0.0f;
  }
}

// ---- pass 1b: reduce partials over lc -> reciprocal row sums ----
__global__ void k1_finalize(const float* __restrict__ partials, float* __restrict__ R,
                            int nl){
  const int tid = blockIdx.x*256 + threadIdx.x;   // 0..2047 = (b*HH+h)*NN+ig
  float ssum = 0.0f;
  for (int lc = 0; lc < nl; ++lc) ssum += partials[lc*(BB*HH*NN) + tid];
  R[tid] = (ssum > 0.0f) ? 1.0f/ssum : 0.0f;
}

// ---- pass 2: recompute logits, write normalized alpha (1KB/wave dwordx4 stores) --
// wave = head; lane owns 4 consecutive l (k in 64 VGPRs, loaded once per block).
__global__ __launch_bounds__(256) void k2_emit(
    const float* __restrict__ qA, const float* __restrict__ kA,
    const void* __restrict__ qm, const void* __restrict__ km,
    const float* __restrict__ R, float* __restrict__ out)
{
  const int mode = compute_mode(qm);
  const int lc = blockIdx.x, it = blockIdx.y, b = blockIdx.z;
  const int t = threadIdx.x, w = t >> 6, ll = t & 63;
  const int hs = __builtin_amdgcn_readfirstlane(w);
  const int ibase = it*TI2;
  const int lbase = lc*256 + ll*4;     // this lane's first l

  // k for 4 rows (own head), scaled; lines shared across the block's waves via L1
  float4 kk[4][4];
  #pragma unroll
  for (int e = 0; e < 4; ++e){
    const float4* kp = (const float4*)(kA + ((size_t)(b*LK + lbase + e))*DD + hs*DHH);
    #pragma unroll
    for (int p = 0; p < 4; ++p){
      float4 v = kp[p];
      v.x *= QK_SCALE; v.y *= QK_SCALE; v.z *= QK_SCALE; v.w *= QK_SCALE;
      kk[e][p] = v;
    }
  }

  unsigned vm[4];
  #pragma unroll
  for (int e = 0; e < 4; ++e){
    const int l = lbase + e;
    const int jn = l >> 7, kn = l & 127;
    const bool kv = (jn != kn) && mget(km, b*LK + l, mode);
    unsigned m = kv ? 0xFFFFFFFFu : 0u;
    if ((unsigned)(jn - ibase) < TI2) m &= ~(1u << (jn - ibase));
    if ((unsigned)(kn - ibase) < TI2) m &= ~(1u << (kn - ibase));
    vm[e] = m;  // q-mask not needed: masked q-rows have R==0
  }

  const float* qbase = qA + ((size_t)(b*NN + ibase))*DD + hs*DHH;
  const float* Rbase = R + (b*HH + hs)*NN + ibase;
  float* op = out + (((size_t)((hs*BB + b)*NN + ibase)) << 14) + lbase;

  #pragma unroll 4
  for (int i = 0; i < TI2; ++i){
    const float4* qp = (const float4*)(qbase + i*DD);   // uniform -> s_load
    const float4 q0 = qp[0], q1 = qp[1], q2 = qp[2], q3 = qp[3];
    const float r = Rbase[i];                           // uniform -> s_load
    float4 o;
    o.x = fexp2((vm[0] & (1u<<i)) ? dot16(q0,q1,q2,q3, kk[0][0],kk[0][1],kk[0][2],kk[0][3]) : -INFINITY) * r;
    o.y = fexp2((vm[1] & (1u<<i)) ? dot16(q0,q1,q2,q3, kk[1][0],kk[1][1],kk[1][2],kk[1][3]) : -INFINITY) * r;
    o.z = fexp2((vm[2] & (1u<<i)) ? dot16(q0,q1,q2,q3, kk[2][0],kk[2][1],kk[2][2],kk[2][3]) : -INFINITY) * r;
    o.w = fexp2((vm[3] & (1u<<i)) ? dot16(q0,q1,q2,q3, kk[3][0],kk[3][1],kk[3][2],kk[3][3]) : -INFINITY) * r;
    *(float4*)(op + (((size_t)i) << 14)) = o;           // 64 lanes -> 1KB contiguous
  }
}

extern "C" void kernel_launch(void* const* d_in, const int* in_sizes, int n_in,
                              void* d_out, int out_size, void* d_ws, size_t ws_size,
                              hipStream_t stream)
{
  const float* qA = (const float*)d_in[0];
  const float* kA = (const float*)d_in[1];
  const void*  qm = d_in[2];
  const void*  km = d_in[3];
  float* out = (float*)d_out;

  // K1 l-split: 128 chunks if workspace allows (1MB partials), else 64 (512KB)
  const size_t need128 = ((size_t)128*BB*HH*NN + BB*HH*NN)*sizeof(float);
  const int nl1 = (ws_size >= need128) ? 128 : 64;

  float* partials = (float*)d_ws;
  float* R        = partials + (size_t)nl1*BB*HH*NN;

  dim3 g1(nl1, NN/TI2, BB);
  k1_rowsum<<<g1, 256, 0, stream>>>(qA, kA, qm, km, partials);
  k1_finalize<<<(BB*HH*NN)/256, 256, 0, stream>>>(partials, R, nl1);
  dim3 g2(LK/256, NN/TI2, BB);     // (64, 4, 4) = 1024 blocks
  k2_emit<<<g2, 256, 0, stream>>>(qA, kA, qm, km, R, out);
}